// Round 8
// baseline (1793.085 us; speedup 1.0000x reference)
//
#include <hip/hip_runtime.h>
#include <cstdint>
#include <cstddef>

// ---------------- constants ----------------
constexpr int BATCH = 64, SEQ = 4096, FEAT = 8, PLEN = 16;
constexpr int DMODEL = 512, NHEAD = 8, NLAYER = 6, DFF = 2048;
constexpr int NPATCH = 256, MROWS = BATCH * NPATCH;   // 16384
constexpr int DK = 64;
constexpr int LDSP = 72;   // padded LDS row stride (u16) for attn tiles

typedef unsigned short u16t;
typedef __bf16 bf16t;
typedef bf16t bf16x8 __attribute__((ext_vector_type(8)));
typedef short s16x4 __attribute__((ext_vector_type(4)));
typedef float f32x4 __attribute__((ext_vector_type(4)));

__device__ __forceinline__ float b2f(u16t u) {
  union { unsigned int ui; float f; } v; v.ui = ((unsigned int)u) << 16; return v.f;
}
__device__ __forceinline__ u16t f2b(float f) {
  union { float f; unsigned int ui; } v; v.f = f;
  return (u16t)((v.ui + 0x7fffu + ((v.ui >> 16) & 1u)) >> 16);
}
__device__ __forceinline__ void g2l16(void* lds, const void* g) {
  __builtin_amdgcn_global_load_lds(
      (__attribute__((address_space(1))) void*)g,
      (__attribute__((address_space(3))) void*)lds, 16, 0, 0);
}

// exact-erf GELU via Abramowitz-Stegun 7.1.26 (|erf err| < 1.5e-7).
__device__ __forceinline__ float gelu_erf(float x) {
  const float z = fabsf(x) * 0.70710678118654752f;
  const float t = __builtin_amdgcn_rcpf(__builtin_fmaf(0.3275911f, z, 1.0f));
  float p = __builtin_fmaf(1.061405429f, t, -1.453152027f);
  p = __builtin_fmaf(p, t, 1.421413741f);
  p = __builtin_fmaf(p, t, -0.284496736f);
  p = __builtin_fmaf(p, t, 0.254829592f);
  const float e = __expf(-z * z);
  const float er = __builtin_fmaf(-p * t, e, 1.0f);   // erf(|z|)
  const float s = copysignf(er, x);
  return 0.5f * x * (1.0f + s);
}

// ---------------- bf16 MFMA GEMM: C[M,N] = A[M,K] @ Bt[N,K]^T (+epilogue) ----
// K-loop (R3-proven): both operands staged via global_load_lds width=16 with
// XOR swizzle; fragment ds_read_b128 conflict-free. MFMA order (R6):
// mfma(bfr, af, acc) -> regs hold 4 consecutive N-cols, lanes hold M-rows.
// R8 epilogue:
//  - bf16 (mode 0/1): SINGLE-phase LDS transpose. Full 128x128 u16 tile fits
//    exactly in the 32KB staging LDS with row stride 128 and a 16B-segment
//    XOR swizzle (seg' = seg ^ (r&7)) instead of padding. ALL 4 waves deposit
//    concurrently (R7's row-phases idled half the waves -> 71->120us FF1
//    regression). Readout: each thread stores one contiguous 128B half-row.
//  - fp32 (mode 2/3): direct float4 stores (quad*4 cols x 4 quads = 64B/row
//    per instr = full sectors already; R6-verified).
// mode 0: Cb = bf16(acc+bias)        mode 1: Cb = bf16(gelu(acc+bias))
// mode 2: Cf += acc+bias (residual)  mode 3: Cf  = acc+bias
__global__ __launch_bounds__(256) void k_gemm(
    const u16t* __restrict__ A, const u16t* __restrict__ Bt,
    const float* __restrict__ bias, const float* __restrict__ b2,
    const float* __restrict__ b3, float* __restrict__ Cf,
    u16t* __restrict__ Cb, int M, int N, int K, int mode)
{
  __shared__ __align__(16) u16t SH[2 * 128 * 64];   // As | Bs, reused by epilogue
  u16t* As = SH;
  u16t* Bs = SH + 128 * 64;
  const int bm = blockIdx.x * 128, bn = blockIdx.y * 128;
  const int tid = threadIdx.x, wave = tid >> 6, lane = tid & 63;
  const int wm = (wave & 1) << 6, wn = (wave >> 1) << 6;
  const int lr = lane & 15, quad = lane >> 4;
  const int srow = lane >> 3;                                // staging row 0..7
  const int scol = (((lane & 7) ^ srow) * 8);                // swizzled source col

  f32x4 acc[4][4] = {};                 // [jN][iM]: reg r -> N-col quad*4+r, lane lr -> M-row
  const u16t* Ab = A + (size_t)bm * K;
  const u16t* Bb = Bt + (size_t)bn * K;

  for (int k0 = 0; k0 < K; k0 += 64) {
    #pragma unroll
    for (int j = 0; j < 4; ++j) {
      const int r0 = (wave * 4 + j) * 8;
      g2l16(&As[r0 * 64], Ab + (size_t)(r0 + srow) * K + k0 + scol);
      g2l16(&Bs[r0 * 64], Bb + (size_t)(r0 + srow) * K + k0 + scol);
    }
    __syncthreads();
    #pragma unroll
    for (int ks = 0; ks < 64; ks += 32) {
      bf16x8 af[4], bfr[4];
      const int segb = ks >> 3;
      #pragma unroll
      for (int i = 0; i < 4; ++i)
        af[i] = *(const bf16x8*)&As[(wm + i * 16 + lr) * 64 + (((segb + quad) ^ (lr & 7)) * 8)];
      #pragma unroll
      for (int j = 0; j < 4; ++j)
        bfr[j] = *(const bf16x8*)&Bs[(wn + j * 16 + lr) * 64 + (((segb + quad) ^ (lr & 7)) * 8)];
      #pragma unroll
      for (int j = 0; j < 4; ++j)
        #pragma unroll
        for (int i = 0; i < 4; ++i)
          acc[j][i] = __builtin_amdgcn_mfma_f32_16x16x32_bf16(bfr[j], af[i], acc[j][i], 0, 0, 0);
    }
    __syncthreads();
  }

  // block-uniform bias base (fused-QKV select)
  const float* bp = bias;
  int reg0 = 0;
  if (bias && b2) { reg0 = (bn >> 9) << 9; bp = reg0 == 0 ? bias : (reg0 == 512 ? b2 : b3); }
  float4 bv[4];
  #pragma unroll
  for (int jN = 0; jN < 4; ++jN) {
    const int gn0 = bn + wn + jN * 16 + quad * 4;
    bv[jN] = bias ? *(const float4*)&bp[gn0 - reg0] : make_float4(0.f, 0.f, 0.f, 0.f);
  }

  if (mode <= 1) {
    // deposit: all 4 waves, disjoint (wm, wn) quadrants of the 128x128 tile
    u16t* E = SH;
    #pragma unroll
    for (int jN = 0; jN < 4; ++jN) {
      const int cl = wn + jN * 16 + quad * 4;
      const int seg = cl >> 3, intra = cl & 7;
      #pragma unroll
      for (int iM = 0; iM < 4; ++iM) {
        const int r = wm + iM * 16 + lr;
        float v0 = acc[jN][iM][0] + bv[jN].x, v1 = acc[jN][iM][1] + bv[jN].y;
        float v2 = acc[jN][iM][2] + bv[jN].z, v3 = acc[jN][iM][3] + bv[jN].w;
        union { u16t h[4]; uint2 u; } pk;
        if (mode == 1) {
          pk.h[0] = f2b(gelu_erf(v0)); pk.h[1] = f2b(gelu_erf(v1));
          pk.h[2] = f2b(gelu_erf(v2)); pk.h[3] = f2b(gelu_erf(v3));
        } else {
          pk.h[0] = f2b(v0); pk.h[1] = f2b(v1); pk.h[2] = f2b(v2); pk.h[3] = f2b(v3);
        }
        *(uint2*)&E[r * 128 + ((seg ^ (r & 7)) << 3) + intra] = pk.u;
      }
    }
    __syncthreads();
    // readout: thread -> (row, 128B half-row), contiguous global stores
    const int r = tid >> 1, halfn = tid & 1;
    u16t* gout = Cb + (size_t)(bm + r) * N + bn + halfn * 64;
    #pragma unroll
    for (int it = 0; it < 8; ++it) {
      const int s = halfn * 8 + it;
      uint4 u = *(const uint4*)&E[r * 128 + ((s ^ (r & 7)) << 3)];
      *(uint4*)(gout + it * 8) = u;
    }
  } else {
    // fp32: direct (already full-sector: 4 quads x 16B = 64B per row per instr)
    #pragma unroll
    for (int jN = 0; jN < 4; ++jN) {
      const int gn0 = bn + wn + jN * 16 + quad * 4;
      #pragma unroll
      for (int iM = 0; iM < 4; ++iM) {
        const int gm = bm + wm + iM * 16 + lr;
        const size_t off = (size_t)gm * N + gn0;
        float v0 = acc[jN][iM][0] + bv[jN].x, v1 = acc[jN][iM][1] + bv[jN].y;
        float v2 = acc[jN][iM][2] + bv[jN].z, v3 = acc[jN][iM][3] + bv[jN].w;
        if (mode == 2) {
          float4 c = *(float4*)(Cf + off);
          c.x += v0; c.y += v1; c.z += v2; c.w += v3;
          *(float4*)(Cf + off) = c;
        } else {
          *(float4*)(Cf + off) = make_float4(v0, v1, v2, v3);
        }
      }
    }
  }
}

// ---------------- weight prep: Wt[orow0+n][k] = bf16(W[k][n] (+ 2*down@up)) -
__global__ __launch_bounds__(256) void k_prep_w(
    const float* __restrict__ W, const float* __restrict__ down,
    const float* __restrict__ up, u16t* __restrict__ Wt, int K, int N,
    size_t ostride, int orow0)
{
  __shared__ float t[32][33];
  const int z = blockIdx.z;
  const float* Wz = W + (size_t)z * K * N;
  u16t* Wtz = Wt + (size_t)z * ostride + (size_t)orow0 * K;
  const int k0 = blockIdx.x * 32, n0 = blockIdx.y * 32;
  const int tx = threadIdx.x & 31, ty = threadIdx.x >> 5;
  for (int i = ty; i < 32; i += 8) {
    const int kk = k0 + i, nn = n0 + tx;
    float v = Wz[(size_t)kk * N + nn];
    if (down) {
      const float* dz = down + (size_t)z * K * 8 + (size_t)kk * 8;
      const float* uz = up + (size_t)z * 8 * N + nn;
      float lv = 0.f;
      #pragma unroll
      for (int r = 0; r < 8; ++r) lv += dz[r] * uz[(size_t)r * N];
      v += 2.0f * lv;   // LORA_SCALING
    }
    t[i][tx] = v;
  }
  __syncthreads();
  for (int i = ty; i < 32; i += 8)
    Wtz[(size_t)(n0 + i) * K + k0 + tx] = f2b(t[tx][i]);
}

// ---------------- patch gather: pt[(b*256+np)*128 + f*16+p] = x[b, np*16+p, f]
__global__ void k_patch(const float* __restrict__ x, u16t* __restrict__ pt) {
  const int idx = blockIdx.x * 256 + threadIdx.x;
  const int col = idx & 127, row = idx >> 7;
  const int f = col >> 4, pp = col & 15;
  const int b = row >> 8, np = row & 255;
  pt[idx] = f2b(x[(((size_t)b << 12) + np * 16 + pp) * 8 + f]);
}

// ---------------- LayerNorm (one wave per 512-row) -> bf16 ----------------
__global__ __launch_bounds__(256) void k_ln(
    const float* __restrict__ xin, const float* __restrict__ w,
    const float* __restrict__ bb, u16t* __restrict__ y)
{
  const int row = blockIdx.x * 4 + (threadIdx.x >> 6);
  const int lane = threadIdx.x & 63;
  const float4* xr = (const float4*)(xin + (size_t)row * 512);
  float4 a = xr[lane * 2], c = xr[lane * 2 + 1];
  float s = a.x + a.y + a.z + a.w + c.x + c.y + c.z + c.w;
  float qq = a.x * a.x + a.y * a.y + a.z * a.z + a.w * a.w +
             c.x * c.x + c.y * c.y + c.z * c.z + c.w * c.w;
  #pragma unroll
  for (int o = 32; o > 0; o >>= 1) { s += __shfl_xor(s, o); qq += __shfl_xor(qq, o); }
  const float mean = s * (1.f / 512.f);
  const float rs = rsqrtf(qq * (1.f / 512.f) - mean * mean + 1e-5f);
  const float4* wr = (const float4*)w; const float4* br = (const float4*)bb;
  float4 w0 = wr[lane * 2], w1 = wr[lane * 2 + 1];
  float4 b0 = br[lane * 2], b1 = br[lane * 2 + 1];
  union { u16t h[8]; uint4 v; } pk;
  pk.h[0] = f2b((a.x - mean) * rs * w0.x + b0.x);
  pk.h[1] = f2b((a.y - mean) * rs * w0.y + b0.y);
  pk.h[2] = f2b((a.z - mean) * rs * w0.z + b0.z);
  pk.h[3] = f2b((a.w - mean) * rs * w0.w + b0.w);
  pk.h[4] = f2b((c.x - mean) * rs * w1.x + b1.x);
  pk.h[5] = f2b((c.y - mean) * rs * w1.y + b1.y);
  pk.h[6] = f2b((c.z - mean) * rs * w1.z + b1.z);
  pk.h[7] = f2b((c.w - mean) * rs * w1.w + b1.w);
  *(uint4*)(y + (size_t)row * 512 + lane * 8) = pk.v;
}

// ---------------- patch LN + pos_enc -> h (fp32) ----------------
__global__ __launch_bounds__(256) void k_ln_pos(
    const float* __restrict__ xin, const float* __restrict__ w,
    const float* __restrict__ bb, const float* __restrict__ pos,
    float* __restrict__ h)
{
  const int row = blockIdx.x * 4 + (threadIdx.x >> 6);
  const int lane = threadIdx.x & 63;
  const float4* xr = (const float4*)(xin + (size_t)row * 512);
  float4 a = xr[lane * 2], c = xr[lane * 2 + 1];
  float s = a.x + a.y + a.z + a.w + c.x + c.y + c.z + c.w;
  float qq = a.x * a.x + a.y * a.y + a.z * a.z + a.w * a.w +
             c.x * c.x + c.y * c.y + c.z * c.z + c.w * c.w;
  #pragma unroll
  for (int o = 32; o > 0; o >>= 1) { s += __shfl_xor(s, o); qq += __shfl_xor(qq, o); }
  const float mean = s * (1.f / 512.f);
  const float rs = rsqrtf(qq * (1.f / 512.f) - mean * mean + 1e-5f);
  const float4* wr = (const float4*)w; const float4* br = (const float4*)bb;
  float4 w0 = wr[lane * 2], w1 = wr[lane * 2 + 1];
  float4 b0 = br[lane * 2], b1 = br[lane * 2 + 1];
  const int np = row & 255;
  const float4* pr = (const float4*)(pos + (size_t)np * 512);
  float4 p0 = pr[lane * 2], p1 = pr[lane * 2 + 1];
  float4 o0, o1;
  o0.x = (a.x - mean) * rs * w0.x + b0.x + p0.x;
  o0.y = (a.y - mean) * rs * w0.y + b0.y + p0.y;
  o0.z = (a.z - mean) * rs * w0.z + b0.z + p0.z;
  o0.w = (a.w - mean) * rs * w0.w + b0.w + p0.w;
  o1.x = (c.x - mean) * rs * w1.x + b1.x + p1.x;
  o1.y = (c.y - mean) * rs * w1.y + b1.y + p1.y;
  o1.z = (c.z - mean) * rs * w1.z + b1.z + p1.z;
  o1.w = (c.w - mean) * rs * w1.w + b1.w + p1.w;
  float4* hr = (float4*)(h + (size_t)row * 512);
  hr[lane * 2] = o0; hr[lane * 2 + 1] = o1;
}

// ---------------- MFMA flash attention -------------------------------------
__global__ __launch_bounds__(256) void k_attn(
    const u16t* __restrict__ qkv, u16t* __restrict__ out)
{
  __shared__ __align__(16) u16t Qs[128 * LDSP];
  __shared__ __align__(16) u16t Ks[64 * LDSP];
  __shared__ __align__(16) u16t Vts[64 * LDSP];

  const int bh = blockIdx.x >> 1, half = blockIdx.x & 1;
  const int b = bh >> 3, hd = bh & 7;
  const int tid = threadIdx.x, wave = tid >> 6, lane = tid & 63;
  const int lr = lane & 15, quad = lane >> 4;

  const size_t rowbase = (size_t)b * 256;
  const u16t* qg = qkv + (rowbase + half * 128) * 1536 + hd * 64;
  const u16t* kg = qkv + rowbase * 1536 + 512 + hd * 64;
  const u16t* vg = qkv + rowbase * 1536 + 1024 + hd * 64;

  #pragma unroll
  for (int i = 0; i < 4; ++i) {
    const int idx = tid + i * 256, row = idx >> 3, seg = idx & 7;
    uint4 u = *(const uint4*)(qg + (size_t)row * 1536 + seg * 8);
    *(uint4*)&Qs[row * LDSP + seg * 8] = u;
  }
  __syncthreads();

  bf16x8 qf[2][2];
  #pragma unroll
  for (int qi = 0; qi < 2; ++qi)
    #pragma unroll
    for (int dh = 0; dh < 2; ++dh)
      qf[qi][dh] = *(const bf16x8*)&Qs[(wave * 32 + qi * 16 + lr) * LDSP + dh * 32 + quad * 8];

  f32x4 O[2][4] = {};
  float mrun[2] = {-1e30f, -1e30f}, lrun[2] = {0.f, 0.f};

  for (int c = 0; c < 4; ++c) {
    __syncthreads();
    #pragma unroll
    for (int i = 0; i < 2; ++i) {
      const int idx = tid + i * 256, row = idx >> 3, seg = idx & 7;
      uint4 u = *(const uint4*)(kg + (size_t)(c * 64 + row) * 1536 + seg * 8);
      *(uint4*)&Ks[row * LDSP + seg * 8] = u;
    }
    {
      const int key = tid & 63, dg = (tid >> 6) * 16;
      const u16t* vrow = vg + (size_t)(c * 64 + key) * 1536 + dg;
      union { u16t h[16]; uint4 v[2]; } tmp;
      tmp.v[0] = *(const uint4*)(vrow);
      tmp.v[1] = *(const uint4*)(vrow + 8);
      #pragma unroll
      for (int i = 0; i < 16; ++i)
        Vts[(dg + i) * LDSP + key] = tmp.h[i];
    }
    __syncthreads();

    #pragma unroll
    for (int qi = 0; qi < 2; ++qi) {
      f32x4 s[4];
      #pragma unroll
      for (int kt = 0; kt < 4; ++kt) {
        f32x4 a = {};
        #pragma unroll
        for (int dh = 0; dh < 2; ++dh) {
          bf16x8 kf = *(const bf16x8*)&Ks[(kt * 16 + lr) * LDSP + dh * 32 + quad * 8];
          a = __builtin_amdgcn_mfma_f32_16x16x32_bf16(kf, qf[qi][dh], a, 0, 0, 0);
        }
        s[kt] = a;
      }
      constexpr float SC = 0.125f * 1.44269504088896f;
      float cmax = -1e30f;
      #pragma unroll
      for (int kt = 0; kt < 4; ++kt)
        #pragma unroll
        for (int r = 0; r < 4; ++r) { s[kt][r] *= SC; cmax = fmaxf(cmax, s[kt][r]); }
      cmax = fmaxf(cmax, __shfl_xor(cmax, 16));
      cmax = fmaxf(cmax, __shfl_xor(cmax, 32));
      const float mn = fmaxf(mrun[qi], cmax);
      const float alpha = exp2f(mrun[qi] - mn);
      mrun[qi] = mn;
      float lsum = 0.f;
      s16x4 pf[4];
      #pragma unroll
      for (int kt = 0; kt < 4; ++kt) {
        #pragma unroll
        for (int r = 0; r < 4; ++r) {
          const u16t eb = f2b(exp2f(s[kt][r] - mn));
          pf[kt][r] = (short)eb;
          lsum += b2f(eb);
        }
      }
      lsum += __shfl_xor(lsum, 16);
      lsum += __shfl_xor(lsum, 32);
      lrun[qi] = lrun[qi] * alpha + lsum;
      #pragma unroll
      for (int dt = 0; dt < 4; ++dt) {
        f32x4 o = O[qi][dt];
        o[0] *= alpha; o[1] *= alpha; o[2] *= alpha; o[3] *= alpha;
        #pragma unroll
        for (int kt = 0; kt < 4; ++kt) {
          s16x4 vf = *(const s16x4*)&Vts[(dt * 16 + lr) * LDSP + kt * 16 + quad * 4];
          o = __builtin_amdgcn_mfma_f32_16x16x16bf16_1k(vf, pf[kt], o, 0, 0, 0);
        }
        O[qi][dt] = o;
      }
    }
  }
  #pragma unroll
  for (int qi = 0; qi < 2; ++qi) {
    const float rl = 1.f / lrun[qi];
    u16t* orow = out + (rowbase + half * 128 + wave * 32 + qi * 16 + lr) * 512 + hd * 64 + quad * 4;
    #pragma unroll
    for (int dt = 0; dt < 4; ++dt) {
      union { u16t h[4]; uint2 v; } pk;
      #pragma unroll
      for (int r = 0; r < 4; ++r) pk.h[r] = f2b(O[qi][dt][r] * rl);
      *(uint2*)(orow + dt * 16) = pk.v;
    }
  }
}

// ---------------- final mean over patches ----------------
__global__ void k_mean(const u16t* __restrict__ y, float* __restrict__ out) {
  const int b = blockIdx.x, d = threadIdx.x;   // 64 x 512
  float s = 0.f;
  #pragma unroll 8
  for (int np = 0; np < 256; ++np) s += b2f(y[((size_t)b * 256 + np) * 512 + d]);
  out[(size_t)b * 512 + d] = s * (1.f / 256.f);
}

// ---------------- host ----------------
extern "C" void kernel_launch(void* const* d_in, const int* in_sizes, int n_in,
                              void* d_out, int out_size, void* d_ws, size_t ws_size,
                              hipStream_t stream)
{
  (void)in_sizes; (void)n_in; (void)out_size;
  const float* x        = (const float*)d_in[0];
  const float* patch_w  = (const float*)d_in[1];
  const float* patch_b  = (const float*)d_in[2];
  const float* patch_ln_w = (const float*)d_in[3];
  const float* patch_ln_b = (const float*)d_in[4];
  const float* pos_enc  = (const float*)d_in[5];
  const float* ln1_w    = (const float*)d_in[6];
  const float* ln1_b    = (const float*)d_in[7];
  const float* q_w      = (const float*)d_in[8];
  const float* q_b      = (const float*)d_in[9];
  const float* k_w      = (const float*)d_in[10];
  const float* k_b      = (const float*)d_in[11];
  const float* v_w      = (const float*)d_in[12];
  const float* v_b      = (const float*)d_in[13];
  const float* lq_down  = (const float*)d_in[14];
  const float* lq_up    = (const float*)d_in[15];
  const float* lk_down  = (const float*)d_in[16];
  const float* lk_up    = (const float*)d_in[17];
  const float* lv_down  = (const float*)d_in[18];
  const float* lv_up    = (const float*)d_in[19];
  const float* o_w      = (const float*)d_in[20];
  const float* o_b      = (const float*)d_in[21];
  const float* ln2_w    = (const float*)d_in[22];
  const float* ln2_b    = (const float*)d_in[23];
  const float* ff1_w    = (const float*)d_in[24];
  const float* ff1_b    = (const float*)d_in[25];
  const float* ff2_w    = (const float*)d_in[26];
  const float* ff2_b    = (const float*)d_in[27];
  const float* norm_w   = (const float*)d_in[28];
  const float* norm_b   = (const float*)d_in[29];
  float* out = (float*)d_out;

  // workspace carve (~148.1 MiB)
  char* p = (char*)d_ws;
  float* h  = (float*)p;  p += (size_t)MROWS * 512 * 4;       // 32 MB
  u16t*  y  = (u16t*)p;   p += (size_t)MROWS * 512 * 2;       // 16 MB
  char* uni = p;          p += (size_t)4 * MROWS * 512 * 2;   // 64 MB union
  u16t* qkvb = (u16t*)uni;                                    // [M,1536] (48 MB)
  u16t* ab = (u16t*)(uni + (size_t)MROWS * 1536 * 2);         // [M,512]  (16 MB)
  u16t* g  = (u16t*)uni;                                      // [M,2048] aliases qkv+ab
  float* pe = (float*)uni;                                    // [M,512] fp32 (pre-LN patch)
  u16t* pt = (u16t*)(uni + (size_t)MROWS * 512 * 4);          // [M,128] after pe
  u16t* wqkv = (u16t*)p; p += (size_t)NLAYER * 1536 * 512 * 2;
  u16t* wo = (u16t*)p; p += (size_t)NLAYER * 512 * 512 * 2;
  u16t* w1 = (u16t*)p; p += (size_t)NLAYER * 512 * 2048 * 2;
  u16t* w2 = (u16t*)p; p += (size_t)NLAYER * 2048 * 512 * 2;
  u16t* wp = (u16t*)p; p += (size_t)512 * 128 * 2;
  if ((size_t)(p - (char*)d_ws) > ws_size) return;

  const dim3 blk(256);
  const size_t QKVS = (size_t)1536 * 512;
  k_prep_w<<<dim3(16, 16, NLAYER), blk, 0, stream>>>(q_w, lq_down, lq_up, wqkv, 512, 512, QKVS, 0);
  k_prep_w<<<dim3(16, 16, NLAYER), blk, 0, stream>>>(k_w, lk_down, lk_up, wqkv, 512, 512, QKVS, 512);
  k_prep_w<<<dim3(16, 16, NLAYER), blk, 0, stream>>>(v_w, lv_down, lv_up, wqkv, 512, 512, QKVS, 1024);
  k_prep_w<<<dim3(16, 16, NLAYER), blk, 0, stream>>>(o_w, nullptr, nullptr, wo, 512, 512, (size_t)512 * 512, 0);
  k_prep_w<<<dim3(16, 64, NLAYER), blk, 0, stream>>>(ff1_w, nullptr, nullptr, w1, 512, 2048, (size_t)512 * 2048, 0);
  k_prep_w<<<dim3(64, 16, NLAYER), blk, 0, stream>>>(ff2_w, nullptr, nullptr, w2, 2048, 512, (size_t)2048 * 512, 0);
  k_prep_w<<<dim3(4, 16, 1),       blk, 0, stream>>>(patch_w, nullptr, nullptr, wp, 128, 512, 0, 0);

  k_patch<<<dim3(MROWS * 128 / 256), blk, 0, stream>>>(x, pt);
  k_gemm<<<dim3(128, 4), blk, 0, stream>>>(pt, wp, patch_b, nullptr, nullptr, pe, nullptr, MROWS, 512, 128, 3);
  k_ln_pos<<<dim3(MROWS / 4), blk, 0, stream>>>(pe, patch_ln_w, patch_ln_b, pos_enc, h);

  for (int i = 0; i < NLAYER; ++i) {
    const size_t ws512 = (size_t)i * 512 * 512, wsff = (size_t)i * 512 * 2048;
    k_ln<<<dim3(MROWS / 4), blk, 0, stream>>>(h, ln1_w + i * 512, ln1_b + i * 512, y);
    k_gemm<<<dim3(128, 12), blk, 0, stream>>>(y, wqkv + i * QKVS, q_b + i * 512, k_b + i * 512,
                                              v_b + i * 512, nullptr, qkvb, MROWS, 1536, 512, 0);
    k_attn<<<dim3(1024), blk, 0, stream>>>(qkvb, ab);
    k_gemm<<<dim3(128, 4), blk, 0, stream>>>(ab, wo + ws512, o_b + i * 512, nullptr, nullptr, h, nullptr, MROWS, 512, 512, 2);
    k_ln<<<dim3(MROWS / 4), blk, 0, stream>>>(h, ln2_w + i * 512, ln2_b + i * 512, y);
    k_gemm<<<dim3(128, 16), blk, 0, stream>>>(y, w1 + wsff, ff1_b + i * 2048, nullptr, nullptr, nullptr, g, MROWS, 2048, 512, 1);
    k_gemm<<<dim3(128, 4), blk, 0, stream>>>(g, w2 + wsff, ff2_b + i * 512, nullptr, nullptr, h, nullptr, MROWS, 512, 2048, 2);
  }
  k_ln<<<dim3(MROWS / 4), blk, 0, stream>>>(h, norm_w, norm_b, y);
  k_mean<<<dim3(BATCH), dim3(512), 0, stream>>>(y, out);
}

// Round 9
// 1599.394 us; speedup vs baseline: 1.1211x; 1.1211x over previous
//
#include <hip/hip_runtime.h>
#include <cstdint>
#include <cstddef>

// ---------------- constants ----------------
constexpr int BATCH = 64, SEQ = 4096, FEAT = 8, PLEN = 16;
constexpr int DMODEL = 512, NHEAD = 8, NLAYER = 6, DFF = 2048;
constexpr int NPATCH = 256, MROWS = BATCH * NPATCH;   // 16384
constexpr int DK = 64;
constexpr int LDSP = 72;   // padded LDS row stride (u16) for attn tiles

typedef unsigned short u16t;
typedef __bf16 bf16t;
typedef bf16t bf16x8 __attribute__((ext_vector_type(8)));
typedef short s16x4 __attribute__((ext_vector_type(4)));
typedef float f32x4 __attribute__((ext_vector_type(4)));

__device__ __forceinline__ float b2f(u16t u) {
  union { unsigned int ui; float f; } v; v.ui = ((unsigned int)u) << 16; return v.f;
}
__device__ __forceinline__ u16t f2b(float f) {
  union { float f; unsigned int ui; } v; v.f = f;
  return (u16t)((v.ui + 0x7fffu + ((v.ui >> 16) & 1u)) >> 16);
}
__device__ __forceinline__ void g2l16(void* lds, const void* g) {
  __builtin_amdgcn_global_load_lds(
      (__attribute__((address_space(1))) void*)g,
      (__attribute__((address_space(3))) void*)lds, 16, 0, 0);
}

// exact-erf GELU via Abramowitz-Stegun 7.1.26 (|erf err| < 1.5e-7).
__device__ __forceinline__ float gelu_erf(float x) {
  const float z = fabsf(x) * 0.70710678118654752f;
  const float t = __builtin_amdgcn_rcpf(__builtin_fmaf(0.3275911f, z, 1.0f));
  float p = __builtin_fmaf(1.061405429f, t, -1.453152027f);
  p = __builtin_fmaf(p, t, 1.421413741f);
  p = __builtin_fmaf(p, t, -0.284496736f);
  p = __builtin_fmaf(p, t, 0.254829592f);
  const float e = __expf(-z * z);
  const float er = __builtin_fmaf(-p * t, e, 1.0f);   // erf(|z|)
  const float s = copysignf(er, x);
  return 0.5f * x * (1.0f + s);
}

// ---------------- bf16 MFMA GEMM: C[M,N] = A[M,K] @ Bt[N,K]^T (+epilogue) ----
// K-loop (R3-proven): both operands staged via global_load_lds width=16 with
// XOR swizzle; fragment ds_read_b128 conflict-free. MFMA order (R6):
// mfma(bfr, af, acc) -> regs hold 4 consecutive N-cols, lanes hold M-rows.
// R9 epilogue (bf16): single-phase LDS transpose (all 4 waves deposit, R8) +
// FULL-SECTOR readout (R7 pattern): per store instruction, 4 consecutive
// lanes cover one contiguous 64B sector of one row. HW fact (R7 vs R8 A/B):
// L2->HBM does NOT merge partial-sector writes across instructions —
// 16B/sector/instr cost 3.5x WRITE_SIZE (228MB vs 65.5MB on FF1).
// fp32 (mode 2/3): direct float4 stores (4 quads x 16B = 64B/row/instr).
// mode 0: Cb = bf16(acc+bias)        mode 1: Cb = bf16(gelu(acc+bias))
// mode 2: Cf += acc+bias (residual)  mode 3: Cf  = acc+bias
__global__ __launch_bounds__(256) void k_gemm(
    const u16t* __restrict__ A, const u16t* __restrict__ Bt,
    const float* __restrict__ bias, const float* __restrict__ b2,
    const float* __restrict__ b3, float* __restrict__ Cf,
    u16t* __restrict__ Cb, int M, int N, int K, int mode)
{
  __shared__ __align__(16) u16t SH[2 * 128 * 64];   // As | Bs, reused by epilogue
  u16t* As = SH;
  u16t* Bs = SH + 128 * 64;
  const int bm = blockIdx.x * 128, bn = blockIdx.y * 128;
  const int tid = threadIdx.x, wave = tid >> 6, lane = tid & 63;
  const int wm = (wave & 1) << 6, wn = (wave >> 1) << 6;
  const int lr = lane & 15, quad = lane >> 4;
  const int srow = lane >> 3;                                // staging row 0..7
  const int scol = (((lane & 7) ^ srow) * 8);                // swizzled source col

  f32x4 acc[4][4] = {};                 // [jN][iM]: reg r -> N-col quad*4+r, lane lr -> M-row
  const u16t* Ab = A + (size_t)bm * K;
  const u16t* Bb = Bt + (size_t)bn * K;

  for (int k0 = 0; k0 < K; k0 += 64) {
    #pragma unroll
    for (int j = 0; j < 4; ++j) {
      const int r0 = (wave * 4 + j) * 8;
      g2l16(&As[r0 * 64], Ab + (size_t)(r0 + srow) * K + k0 + scol);
      g2l16(&Bs[r0 * 64], Bb + (size_t)(r0 + srow) * K + k0 + scol);
    }
    __syncthreads();
    #pragma unroll
    for (int ks = 0; ks < 64; ks += 32) {
      bf16x8 af[4], bfr[4];
      const int segb = ks >> 3;
      #pragma unroll
      for (int i = 0; i < 4; ++i)
        af[i] = *(const bf16x8*)&As[(wm + i * 16 + lr) * 64 + (((segb + quad) ^ (lr & 7)) * 8)];
      #pragma unroll
      for (int j = 0; j < 4; ++j)
        bfr[j] = *(const bf16x8*)&Bs[(wn + j * 16 + lr) * 64 + (((segb + quad) ^ (lr & 7)) * 8)];
      #pragma unroll
      for (int j = 0; j < 4; ++j)
        #pragma unroll
        for (int i = 0; i < 4; ++i)
          acc[j][i] = __builtin_amdgcn_mfma_f32_16x16x32_bf16(bfr[j], af[i], acc[j][i], 0, 0, 0);
    }
    __syncthreads();
  }

  // block-uniform bias base (fused-QKV select)
  const float* bp = bias;
  int reg0 = 0;
  if (bias && b2) { reg0 = (bn >> 9) << 9; bp = reg0 == 0 ? bias : (reg0 == 512 ? b2 : b3); }
  float4 bv[4];
  #pragma unroll
  for (int jN = 0; jN < 4; ++jN) {
    const int gn0 = bn + wn + jN * 16 + quad * 4;
    bv[jN] = bias ? *(const float4*)&bp[gn0 - reg0] : make_float4(0.f, 0.f, 0.f, 0.f);
  }

  if (mode <= 1) {
    // deposit: all 4 waves, disjoint (wm, wn) quadrants of the 128x128 tile
    u16t* E = SH;
    #pragma unroll
    for (int jN = 0; jN < 4; ++jN) {
      const int cl = wn + jN * 16 + quad * 4;
      const int seg = cl >> 3, intra = cl & 7;
      #pragma unroll
      for (int iM = 0; iM < 4; ++iM) {
        const int r = wm + iM * 16 + lr;
        float v0 = acc[jN][iM][0] + bv[jN].x, v1 = acc[jN][iM][1] + bv[jN].y;
        float v2 = acc[jN][iM][2] + bv[jN].z, v3 = acc[jN][iM][3] + bv[jN].w;
        union { u16t h[4]; uint2 u; } pk;
        if (mode == 1) {
          pk.h[0] = f2b(gelu_erf(v0)); pk.h[1] = f2b(gelu_erf(v1));
          pk.h[2] = f2b(gelu_erf(v2)); pk.h[3] = f2b(gelu_erf(v3));
        } else {
          pk.h[0] = f2b(v0); pk.h[1] = f2b(v1); pk.h[2] = f2b(v2); pk.h[3] = f2b(v3);
        }
        *(uint2*)&E[r * 128 + ((seg ^ (r & 7)) << 3) + intra] = pk.u;
      }
    }
    __syncthreads();
    // readout: per instruction, 4 consecutive lanes -> one full 64B sector of
    // one row (R7-verified full-sector pattern); 2 passes cover 128 rows.
    const int rr = tid >> 2, s0 = tid & 3;
    #pragma unroll
    for (int pass = 0; pass < 2; ++pass) {
      const int r = pass * 64 + rr;
      u16t* gout = Cb + (size_t)(bm + r) * N + bn;
      #pragma unroll
      for (int it = 0; it < 4; ++it) {
        const int s = s0 + it * 4;
        uint4 u = *(const uint4*)&E[r * 128 + ((s ^ (r & 7)) << 3)];
        *(uint4*)(gout + s * 8) = u;
      }
    }
  } else {
    // fp32: direct (full-sector: 4 quads x 16B = 64B per row per instr)
    #pragma unroll
    for (int jN = 0; jN < 4; ++jN) {
      const int gn0 = bn + wn + jN * 16 + quad * 4;
      #pragma unroll
      for (int iM = 0; iM < 4; ++iM) {
        const int gm = bm + wm + iM * 16 + lr;
        const size_t off = (size_t)gm * N + gn0;
        float v0 = acc[jN][iM][0] + bv[jN].x, v1 = acc[jN][iM][1] + bv[jN].y;
        float v2 = acc[jN][iM][2] + bv[jN].z, v3 = acc[jN][iM][3] + bv[jN].w;
        if (mode == 2) {
          float4 c = *(float4*)(Cf + off);
          c.x += v0; c.y += v1; c.z += v2; c.w += v3;
          *(float4*)(Cf + off) = c;
        } else {
          *(float4*)(Cf + off) = make_float4(v0, v1, v2, v3);
        }
      }
    }
  }
}

// ---------------- weight prep: Wt[orow0+n][k] = bf16(W[k][n] (+ 2*down@up)) -
__global__ __launch_bounds__(256) void k_prep_w(
    const float* __restrict__ W, const float* __restrict__ down,
    const float* __restrict__ up, u16t* __restrict__ Wt, int K, int N,
    size_t ostride, int orow0)
{
  __shared__ float t[32][33];
  const int z = blockIdx.z;
  const float* Wz = W + (size_t)z * K * N;
  u16t* Wtz = Wt + (size_t)z * ostride + (size_t)orow0 * K;
  const int k0 = blockIdx.x * 32, n0 = blockIdx.y * 32;
  const int tx = threadIdx.x & 31, ty = threadIdx.x >> 5;
  for (int i = ty; i < 32; i += 8) {
    const int kk = k0 + i, nn = n0 + tx;
    float v = Wz[(size_t)kk * N + nn];
    if (down) {
      const float* dz = down + (size_t)z * K * 8 + (size_t)kk * 8;
      const float* uz = up + (size_t)z * 8 * N + nn;
      float lv = 0.f;
      #pragma unroll
      for (int r = 0; r < 8; ++r) lv += dz[r] * uz[(size_t)r * N];
      v += 2.0f * lv;   // LORA_SCALING
    }
    t[i][tx] = v;
  }
  __syncthreads();
  for (int i = ty; i < 32; i += 8)
    Wtz[(size_t)(n0 + i) * K + k0 + tx] = f2b(t[tx][i]);
}

// ---------------- patch gather: pt[(b*256+np)*128 + f*16+p] = x[b, np*16+p, f]
__global__ void k_patch(const float* __restrict__ x, u16t* __restrict__ pt) {
  const int idx = blockIdx.x * 256 + threadIdx.x;
  const int col = idx & 127, row = idx >> 7;
  const int f = col >> 4, pp = col & 15;
  const int b = row >> 8, np = row & 255;
  pt[idx] = f2b(x[(((size_t)b << 12) + np * 16 + pp) * 8 + f]);
}

// ---------------- LayerNorm (one wave per 512-row) -> bf16 ----------------
__global__ __launch_bounds__(256) void k_ln(
    const float* __restrict__ xin, const float* __restrict__ w,
    const float* __restrict__ bb, u16t* __restrict__ y)
{
  const int row = blockIdx.x * 4 + (threadIdx.x >> 6);
  const int lane = threadIdx.x & 63;
  const float4* xr = (const float4*)(xin + (size_t)row * 512);
  float4 a = xr[lane * 2], c = xr[lane * 2 + 1];
  float s = a.x + a.y + a.z + a.w + c.x + c.y + c.z + c.w;
  float qq = a.x * a.x + a.y * a.y + a.z * a.z + a.w * a.w +
             c.x * c.x + c.y * c.y + c.z * c.z + c.w * c.w;
  #pragma unroll
  for (int o = 32; o > 0; o >>= 1) { s += __shfl_xor(s, o); qq += __shfl_xor(qq, o); }
  const float mean = s * (1.f / 512.f);
  const float rs = rsqrtf(qq * (1.f / 512.f) - mean * mean + 1e-5f);
  const float4* wr = (const float4*)w; const float4* br = (const float4*)bb;
  float4 w0 = wr[lane * 2], w1 = wr[lane * 2 + 1];
  float4 b0 = br[lane * 2], b1 = br[lane * 2 + 1];
  union { u16t h[8]; uint4 v; } pk;
  pk.h[0] = f2b((a.x - mean) * rs * w0.x + b0.x);
  pk.h[1] = f2b((a.y - mean) * rs * w0.y + b0.y);
  pk.h[2] = f2b((a.z - mean) * rs * w0.z + b0.z);
  pk.h[3] = f2b((a.w - mean) * rs * w0.w + b0.w);
  pk.h[4] = f2b((c.x - mean) * rs * w1.x + b1.x);
  pk.h[5] = f2b((c.y - mean) * rs * w1.y + b1.y);
  pk.h[6] = f2b((c.z - mean) * rs * w1.z + b1.z);
  pk.h[7] = f2b((c.w - mean) * rs * w1.w + b1.w);
  *(uint4*)(y + (size_t)row * 512 + lane * 8) = pk.v;
}

// ---------------- patch LN + pos_enc -> h (fp32) ----------------
__global__ __launch_bounds__(256) void k_ln_pos(
    const float* __restrict__ xin, const float* __restrict__ w,
    const float* __restrict__ bb, const float* __restrict__ pos,
    float* __restrict__ h)
{
  const int row = blockIdx.x * 4 + (threadIdx.x >> 6);
  const int lane = threadIdx.x & 63;
  const float4* xr = (const float4*)(xin + (size_t)row * 512);
  float4 a = xr[lane * 2], c = xr[lane * 2 + 1];
  float s = a.x + a.y + a.z + a.w + c.x + c.y + c.z + c.w;
  float qq = a.x * a.x + a.y * a.y + a.z * a.z + a.w * a.w +
             c.x * c.x + c.y * c.y + c.z * c.z + c.w * c.w;
  #pragma unroll
  for (int o = 32; o > 0; o >>= 1) { s += __shfl_xor(s, o); qq += __shfl_xor(qq, o); }
  const float mean = s * (1.f / 512.f);
  const float rs = rsqrtf(qq * (1.f / 512.f) - mean * mean + 1e-5f);
  const float4* wr = (const float4*)w; const float4* br = (const float4*)bb;
  float4 w0 = wr[lane * 2], w1 = wr[lane * 2 + 1];
  float4 b0 = br[lane * 2], b1 = br[lane * 2 + 1];
  const int np = row & 255;
  const float4* pr = (const float4*)(pos + (size_t)np * 512);
  float4 p0 = pr[lane * 2], p1 = pr[lane * 2 + 1];
  float4 o0, o1;
  o0.x = (a.x - mean) * rs * w0.x + b0.x + p0.x;
  o0.y = (a.y - mean) * rs * w0.y + b0.y + p0.y;
  o0.z = (a.z - mean) * rs * w0.z + b0.z + p0.z;
  o0.w = (a.w - mean) * rs * w0.w + b0.w + p0.w;
  o1.x = (c.x - mean) * rs * w1.x + b1.x + p1.x;
  o1.y = (c.y - mean) * rs * w1.y + b1.y + p1.y;
  o1.z = (c.z - mean) * rs * w1.z + b1.z + p1.z;
  o1.w = (c.w - mean) * rs * w1.w + b1.w + p1.w;
  float4* hr = (float4*)(h + (size_t)row * 512);
  hr[lane * 2] = o0; hr[lane * 2 + 1] = o1;
}

// ---------------- MFMA flash attention -------------------------------------
__global__ __launch_bounds__(256) void k_attn(
    const u16t* __restrict__ qkv, u16t* __restrict__ out)
{
  __shared__ __align__(16) u16t Qs[128 * LDSP];
  __shared__ __align__(16) u16t Ks[64 * LDSP];
  __shared__ __align__(16) u16t Vts[64 * LDSP];

  const int bh = blockIdx.x >> 1, half = blockIdx.x & 1;
  const int b = bh >> 3, hd = bh & 7;
  const int tid = threadIdx.x, wave = tid >> 6, lane = tid & 63;
  const int lr = lane & 15, quad = lane >> 4;

  const size_t rowbase = (size_t)b * 256;
  const u16t* qg = qkv + (rowbase + half * 128) * 1536 + hd * 64;
  const u16t* kg = qkv + rowbase * 1536 + 512 + hd * 64;
  const u16t* vg = qkv + rowbase * 1536 + 1024 + hd * 64;

  #pragma unroll
  for (int i = 0; i < 4; ++i) {
    const int idx = tid + i * 256, row = idx >> 3, seg = idx & 7;
    uint4 u = *(const uint4*)(qg + (size_t)row * 1536 + seg * 8);
    *(uint4*)&Qs[row * LDSP + seg * 8] = u;
  }
  __syncthreads();

  bf16x8 qf[2][2];
  #pragma unroll
  for (int qi = 0; qi < 2; ++qi)
    #pragma unroll
    for (int dh = 0; dh < 2; ++dh)
      qf[qi][dh] = *(const bf16x8*)&Qs[(wave * 32 + qi * 16 + lr) * LDSP + dh * 32 + quad * 8];

  f32x4 O[2][4] = {};
  float mrun[2] = {-1e30f, -1e30f}, lrun[2] = {0.f, 0.f};

  for (int c = 0; c < 4; ++c) {
    __syncthreads();
    #pragma unroll
    for (int i = 0; i < 2; ++i) {
      const int idx = tid + i * 256, row = idx >> 3, seg = idx & 7;
      uint4 u = *(const uint4*)(kg + (size_t)(c * 64 + row) * 1536 + seg * 8);
      *(uint4*)&Ks[row * LDSP + seg * 8] = u;
    }
    {
      const int key = tid & 63, dg = (tid >> 6) * 16;
      const u16t* vrow = vg + (size_t)(c * 64 + key) * 1536 + dg;
      union { u16t h[16]; uint4 v[2]; } tmp;
      tmp.v[0] = *(const uint4*)(vrow);
      tmp.v[1] = *(const uint4*)(vrow + 8);
      #pragma unroll
      for (int i = 0; i < 16; ++i)
        Vts[(dg + i) * LDSP + key] = tmp.h[i];
    }
    __syncthreads();

    #pragma unroll
    for (int qi = 0; qi < 2; ++qi) {
      f32x4 s[4];
      #pragma unroll
      for (int kt = 0; kt < 4; ++kt) {
        f32x4 a = {};
        #pragma unroll
        for (int dh = 0; dh < 2; ++dh) {
          bf16x8 kf = *(const bf16x8*)&Ks[(kt * 16 + lr) * LDSP + dh * 32 + quad * 8];
          a = __builtin_amdgcn_mfma_f32_16x16x32_bf16(kf, qf[qi][dh], a, 0, 0, 0);
        }
        s[kt] = a;
      }
      constexpr float SC = 0.125f * 1.44269504088896f;
      float cmax = -1e30f;
      #pragma unroll
      for (int kt = 0; kt < 4; ++kt)
        #pragma unroll
        for (int r = 0; r < 4; ++r) { s[kt][r] *= SC; cmax = fmaxf(cmax, s[kt][r]); }
      cmax = fmaxf(cmax, __shfl_xor(cmax, 16));
      cmax = fmaxf(cmax, __shfl_xor(cmax, 32));
      const float mn = fmaxf(mrun[qi], cmax);
      const float alpha = exp2f(mrun[qi] - mn);
      mrun[qi] = mn;
      float lsum = 0.f;
      s16x4 pf[4];
      #pragma unroll
      for (int kt = 0; kt < 4; ++kt) {
        #pragma unroll
        for (int r = 0; r < 4; ++r) {
          const u16t eb = f2b(exp2f(s[kt][r] - mn));
          pf[kt][r] = (short)eb;
          lsum += b2f(eb);
        }
      }
      lsum += __shfl_xor(lsum, 16);
      lsum += __shfl_xor(lsum, 32);
      lrun[qi] = lrun[qi] * alpha + lsum;
      #pragma unroll
      for (int dt = 0; dt < 4; ++dt) {
        f32x4 o = O[qi][dt];
        o[0] *= alpha; o[1] *= alpha; o[2] *= alpha; o[3] *= alpha;
        #pragma unroll
        for (int kt = 0; kt < 4; ++kt) {
          s16x4 vf = *(const s16x4*)&Vts[(dt * 16 + lr) * LDSP + kt * 16 + quad * 4];
          o = __builtin_amdgcn_mfma_f32_16x16x16bf16_1k(vf, pf[kt], o, 0, 0, 0);
        }
        O[qi][dt] = o;
      }
    }
  }
  #pragma unroll
  for (int qi = 0; qi < 2; ++qi) {
    const float rl = 1.f / lrun[qi];
    u16t* orow = out + (rowbase + half * 128 + wave * 32 + qi * 16 + lr) * 512 + hd * 64 + quad * 4;
    #pragma unroll
    for (int dt = 0; dt < 4; ++dt) {
      union { u16t h[4]; uint2 v; } pk;
      #pragma unroll
      for (int r = 0; r < 4; ++r) pk.h[r] = f2b(O[qi][dt][r] * rl);
      *(uint2*)(orow + dt * 16) = pk.v;
    }
  }
}

// ---------------- final mean over patches ----------------
__global__ void k_mean(const u16t* __restrict__ y, float* __restrict__ out) {
  const int b = blockIdx.x, d = threadIdx.x;   // 64 x 512
  float s = 0.f;
  #pragma unroll 8
  for (int np = 0; np < 256; ++np) s += b2f(y[((size_t)b * 256 + np) * 512 + d]);
  out[(size_t)b * 512 + d] = s * (1.f / 256.f);
}

// ---------------- host ----------------
extern "C" void kernel_launch(void* const* d_in, const int* in_sizes, int n_in,
                              void* d_out, int out_size, void* d_ws, size_t ws_size,
                              hipStream_t stream)
{
  (void)in_sizes; (void)n_in; (void)out_size;
  const float* x        = (const float*)d_in[0];
  const float* patch_w  = (const float*)d_in[1];
  const float* patch_b  = (const float*)d_in[2];
  const float* patch_ln_w = (const float*)d_in[3];
  const float* patch_ln_b = (const float*)d_in[4];
  const float* pos_enc  = (const float*)d_in[5];
  const float* ln1_w    = (const float*)d_in[6];
  const float* ln1_b    = (const float*)d_in[7];
  const float* q_w      = (const float*)d_in[8];
  const float* q_b      = (const float*)d_in[9];
  const float* k_w      = (const float*)d_in[10];
  const float* k_b      = (const float*)d_in[11];
  const float* v_w      = (const float*)d_in[12];
  const float* v_b      = (const float*)d_in[13];
  const float* lq_down  = (const float*)d_in[14];
  const float* lq_up    = (const float*)d_in[15];
  const float* lk_down  = (const float*)d_in[16];
  const float* lk_up    = (const float*)d_in[17];
  const float* lv_down  = (const float*)d_in[18];
  const float* lv_up    = (const float*)d_in[19];
  const float* o_w      = (const float*)d_in[20];
  const float* o_b      = (const float*)d_in[21];
  const float* ln2_w    = (const float*)d_in[22];
  const float* ln2_b    = (const float*)d_in[23];
  const float* ff1_w    = (const float*)d_in[24];
  const float* ff1_b    = (const float*)d_in[25];
  const float* ff2_w    = (const float*)d_in[26];
  const float* ff2_b    = (const float*)d_in[27];
  const float* norm_w   = (const float*)d_in[28];
  const float* norm_b   = (const float*)d_in[29];
  float* out = (float*)d_out;

  // workspace carve (~148.1 MiB)
  char* p = (char*)d_ws;
  float* h  = (float*)p;  p += (size_t)MROWS * 512 * 4;       // 32 MB
  u16t*  y  = (u16t*)p;   p += (size_t)MROWS * 512 * 2;       // 16 MB
  char* uni = p;          p += (size_t)4 * MROWS * 512 * 2;   // 64 MB union
  u16t* qkvb = (u16t*)uni;                                    // [M,1536] (48 MB)
  u16t* ab = (u16t*)(uni + (size_t)MROWS * 1536 * 2);         // [M,512]  (16 MB)
  u16t* g  = (u16t*)uni;                                      // [M,2048] aliases qkv+ab
  float* pe = (float*)uni;                                    // [M,512] fp32 (pre-LN patch)
  u16t* pt = (u16t*)(uni + (size_t)MROWS * 512 * 4);          // [M,128] after pe
  u16t* wqkv = (u16t*)p; p += (size_t)NLAYER * 1536 * 512 * 2;
  u16t* wo = (u16t*)p; p += (size_t)NLAYER * 512 * 512 * 2;
  u16t* w1 = (u16t*)p; p += (size_t)NLAYER * 512 * 2048 * 2;
  u16t* w2 = (u16t*)p; p += (size_t)NLAYER * 2048 * 512 * 2;
  u16t* wp = (u16t*)p; p += (size_t)512 * 128 * 2;
  if ((size_t)(p - (char*)d_ws) > ws_size) return;

  const dim3 blk(256);
  const size_t QKVS = (size_t)1536 * 512;
  k_prep_w<<<dim3(16, 16, NLAYER), blk, 0, stream>>>(q_w, lq_down, lq_up, wqkv, 512, 512, QKVS, 0);
  k_prep_w<<<dim3(16, 16, NLAYER), blk, 0, stream>>>(k_w, lk_down, lk_up, wqkv, 512, 512, QKVS, 512);
  k_prep_w<<<dim3(16, 16, NLAYER), blk, 0, stream>>>(v_w, lv_down, lv_up, wqkv, 512, 512, QKVS, 1024);
  k_prep_w<<<dim3(16, 16, NLAYER), blk, 0, stream>>>(o_w, nullptr, nullptr, wo, 512, 512, (size_t)512 * 512, 0);
  k_prep_w<<<dim3(16, 64, NLAYER), blk, 0, stream>>>(ff1_w, nullptr, nullptr, w1, 512, 2048, (size_t)512 * 2048, 0);
  k_prep_w<<<dim3(64, 16, NLAYER), blk, 0, stream>>>(ff2_w, nullptr, nullptr, w2, 2048, 512, (size_t)2048 * 512, 0);
  k_prep_w<<<dim3(4, 16, 1),       blk, 0, stream>>>(patch_w, nullptr, nullptr, wp, 128, 512, 0, 0);

  k_patch<<<dim3(MROWS * 128 / 256), blk, 0, stream>>>(x, pt);
  k_gemm<<<dim3(128, 4), blk, 0, stream>>>(pt, wp, patch_b, nullptr, nullptr, pe, nullptr, MROWS, 512, 128, 3);
  k_ln_pos<<<dim3(MROWS / 4), blk, 0, stream>>>(pe, patch_ln_w, patch_ln_b, pos_enc, h);

  for (int i = 0; i < NLAYER; ++i) {
    const size_t ws512 = (size_t)i * 512 * 512, wsff = (size_t)i * 512 * 2048;
    k_ln<<<dim3(MROWS / 4), blk, 0, stream>>>(h, ln1_w + i * 512, ln1_b + i * 512, y);
    k_gemm<<<dim3(128, 12), blk, 0, stream>>>(y, wqkv + i * QKVS, q_b + i * 512, k_b + i * 512,
                                              v_b + i * 512, nullptr, qkvb, MROWS, 1536, 512, 0);
    k_attn<<<dim3(1024), blk, 0, stream>>>(qkvb, ab);
    k_gemm<<<dim3(128, 4), blk, 0, stream>>>(ab, wo + ws512, o_b + i * 512, nullptr, nullptr, h, nullptr, MROWS, 512, 512, 2);
    k_ln<<<dim3(MROWS / 4), blk, 0, stream>>>(h, ln2_w + i * 512, ln2_b + i * 512, y);
    k_gemm<<<dim3(128, 16), blk, 0, stream>>>(y, w1 + wsff, ff1_b + i * 2048, nullptr, nullptr, nullptr, g, MROWS, 2048, 512, 1);
    k_gemm<<<dim3(128, 4), blk, 0, stream>>>(g, w2 + wsff, ff2_b + i * 512, nullptr, nullptr, h, nullptr, MROWS, 512, 2048, 2);
  }
  k_ln<<<dim3(MROWS / 4), blk, 0, stream>>>(h, norm_w, norm_b, y);
  k_mean<<<dim3(BATCH), dim3(512), 0, stream>>>(y, out);
}